// Round 4
// baseline (68.681 us; speedup 1.0000x reference)
//
#include <hip/hip_runtime.h>

typedef float  f32x4  __attribute__((ext_vector_type(4)));
typedef float  f32x2  __attribute__((ext_vector_type(2)));
typedef short  bf16x8 __attribute__((ext_vector_type(8)));
typedef int    i32x4  __attribute__((ext_vector_type(4)));

#define NNODE 3072
#define DIN   128
#define DOUT  128
#define NREL  3
#define NH    4
#define HD    32
#define KCH   48      // K chunks of 64
#define CHB   9216    // ushorts per B chunk (9 tiles * 2 steps * 64 lanes * 8)

static __device__ __forceinline__ unsigned short f2bf(float v) {
  unsigned u = __builtin_bit_cast(unsigned, v);
  u += 0x7FFFu + ((u >> 16) & 1u);          // round-to-nearest-even
  return (unsigned short)(u >> 16);
}

// ---------------- K0: init out = bias ----------------
__global__ __launch_bounds__(256, 1) void k0_init(
    const float* __restrict__ bias, float* __restrict__ out)
{
  const int tid = blockIdx.x * 256 + threadIdx.x;   // 3072*128/4 elems
  f32x4 b = *(const f32x4*)(bias + (tid & 31) * 4);
  *((f32x4*)out + tid) = b;
}

// ---------------- K1: t = F * W_r^T, attention scalars, build B in MFMA-fragment order ----
// grid (48, 3), block 256. Each block: one relation, 64 k-rows (= one 64-K chunk). (validated)
__global__ __launch_bounds__(256, 1) void k1_prep(
    const float* __restrict__ feat, const float* __restrict__ W,
    const float* __restrict__ av, unsigned short* __restrict__ Mt,
    float* __restrict__ Es)
{
  const int jt = blockIdx.x;     // 0..47  (= K chunk index)
  const int r  = blockIdx.y;     // 0..2
  const int t  = threadIdx.x;    // 0..255
  const int jb = jt * 64;

  __shared__ float Wl[128 * 130];
  __shared__ float Fl[64 * 129];
  __shared__ float Tl[64 * 129];
  __shared__ float El[64 * 5];

  const float* Wr = W + r * DOUT * DIN;
  for (int idx = t * 4; idx < DOUT * DIN; idx += 1024) {
    float4 v = *(const float4*)(Wr + idx);
    int o = idx >> 7, k = idx & 127;
    float* d = Wl + o * 130 + k;
    d[0] = v.x; d[1] = v.y; d[2] = v.z; d[3] = v.w;
  }
  for (int idx = t * 4; idx < 64 * DIN; idx += 1024) {
    float4 v = *(const float4*)(feat + (size_t)jb * DIN + idx);
    int n = idx >> 7, k = idx & 127;
    float* d = Fl + n * 129 + k;
    d[0] = v.x; d[1] = v.y; d[2] = v.z; d[3] = v.w;
  }
  __syncthreads();

  {
    const int ng = t & 15, og = t >> 4;
    float acc[4][8] = {};
    for (int k = 0; k < DIN; k += 4) {
      float wv[4][8];
      #pragma unroll
      for (int oo = 0; oo < 8; ++oo) {
        const float* wr2 = Wl + (og * 8 + oo) * 130 + k;
        f32x2 a01 = *(const f32x2*)wr2;
        f32x2 a23 = *(const f32x2*)(wr2 + 2);
        wv[0][oo] = a01[0]; wv[1][oo] = a01[1];
        wv[2][oo] = a23[0]; wv[3][oo] = a23[1];
      }
      #pragma unroll
      for (int nn = 0; nn < 4; ++nn) {
        const float* fr = Fl + (ng * 4 + nn) * 129 + k;
        float f0 = fr[0], f1 = fr[1], f2 = fr[2], f3 = fr[3];
        #pragma unroll
        for (int oo = 0; oo < 8; ++oo) {
          float s = acc[nn][oo];
          s = fmaf(f0, wv[0][oo], s);
          s = fmaf(f1, wv[1][oo], s);
          s = fmaf(f2, wv[2][oo], s);
          s = fmaf(f3, wv[3][oo], s);
          acc[nn][oo] = s;
        }
      }
    }
    #pragma unroll
    for (int nn = 0; nn < 4; ++nn)
      #pragma unroll
      for (int oo = 0; oo < 8; ++oo)
        Tl[(ng * 4 + nn) * 129 + og * 8 + oo] = acc[nn][oo];
  }
  __syncthreads();

  {
    const int n = t & 63, h = t >> 6;
    const float* tr = Tl + n * 129 + h * HD;
    const float* as = av + r * 2 * HD;
    float ss = 0.f, sd = 0.f;
    #pragma unroll
    for (int d = 0; d < HD; ++d) {
      float tvv = tr[d];
      ss = fmaf(tvv, as[d],      ss);
      sd = fmaf(tvv, as[HD + d], sd);
    }
    Es[((size_t)r * NNODE + jb + n) * NH + h] = expf(ss);
    El[n * 5 + h] = expf(sd);
  }
  __syncthreads();

  {
    // B fragment order: chunk = [tile nt][step s][lane = k8*16 + (c&15)][elem = j&7]
    const int n = t & 63, cb = t >> 6;   // j = jb + n
    unsigned short* base = Mt + ((size_t)r * KCH + jt) * CHB;
    const int s = n >> 5, k8 = (n >> 3) & 3, elem = n & 7;
    const int lanebase = k8 * 16;
    #pragma unroll
    for (int ci = 0; ci < 36; ++ci) {
      int c = cb * 36 + ci;
      float v;
      if (c < DOUT)            v = Tl[n * 129 + c] * El[n * 5 + (c >> 5)];
      else if (c < DOUT + NH)  v = El[n * 5 + (c - DOUT)];
      else if (c == DOUT + NH) v = 1.0f;
      else                     v = 0.0f;
      int nt = c >> 4;
      base[(nt * 2 + s) * 512 + (lanebase + (c & 15)) * 8 + elem] = f2bf(v);
    }
  }
}

// ---------------- K2: counted-vmcnt pipelined A@M, fused finalize ----------------
// grid (96, 3), block 256 = 4 waves. Block: 32 rows x 144 cols, full K.
// Per wave per chunk: 2 global_load_lds (A) + 6 global_load_dwordx4 (B) = 8 loads, uniform.
// Main loop: s_waitcnt vmcnt(8) -> s_barrier -> stage(kc+2) -> compute(kc). Never vmcnt(0).
__global__ __launch_bounds__(256, 2) void k2_agg(
    const int* __restrict__ adj, const unsigned short* __restrict__ Mt,
    const float* __restrict__ Es, float* __restrict__ out)
{
  const int it = blockIdx.x;    // 0..95
  const int r  = blockIdx.y;    // 0..2
  const int t  = threadIdx.x;   // 0..255
  const int wv = t >> 6;        // 0..3
  const int l  = t & 63;
  const int l16 = l & 15, l4 = l >> 4;
  const int ib = it * 32;

  __shared__ __align__(16) int Ash[3 * 2048];   // 3 bufs x 32 rows x 64 ints (16B-chunk XOR swz)
  __shared__ float red[32 * 145];
  __shared__ float coefL[128];

  // --- A staging maps: thread t -> row t>>4 (inst0) / 16+(t>>4) (inst1), swizzled src chunk ---
  const size_t adjBase = (size_t)r * NNODE * NNODE + (size_t)ib * NNODE;
  const int srow = t >> 4;
  const int schunk = (t & 15) ^ (srow & 7);
  const int* src0 = adj + adjBase + (size_t)srow * NNODE + schunk * 4;
  const int* src1 = src0 + 16 * NNODE;          // row+16 keeps same (row&7)
  const int d0 = wv * 256;                      // int offset within buf, inst0
  const int d1 = wv * 256 + 1024;               // inst1

  #define STAGEA(bufi, kc) do {                                                   \
    __builtin_amdgcn_global_load_lds(                                             \
        (const __attribute__((address_space(1))) void*)(src0 + (kc) * 64),        \
        (__attribute__((address_space(3))) void*)&Ash[(bufi) * 2048 + d0], 16, 0, 0); \
    __builtin_amdgcn_global_load_lds(                                             \
        (const __attribute__((address_space(1))) void*)(src1 + (kc) * 64),        \
        (__attribute__((address_space(3))) void*)&Ash[(bufi) * 2048 + d1], 16, 0, 0); \
  } while (0)

  // --- B: wave wv owns tiles {2wv, 2wv+1} + replicated tile 8 (V/deg); 6 loads/chunk ---
  const unsigned short* mtr = Mt + (size_t)r * KCH * CHB + (size_t)l * 8;
  #define LOADB(B, kc) do {                                                       \
    const unsigned short* p_ = mtr + (size_t)(kc) * CHB;                          \
    B[0] = *(const bf16x8*)(p_ + (4 * wv + 0) * 512);                             \
    B[1] = *(const bf16x8*)(p_ + (4 * wv + 1) * 512);                             \
    B[2] = *(const bf16x8*)(p_ + (4 * wv + 2) * 512);                             \
    B[3] = *(const bf16x8*)(p_ + (4 * wv + 3) * 512);                             \
    B[4] = *(const bf16x8*)(p_ + 16 * 512);                                       \
    B[5] = *(const bf16x8*)(p_ + 17 * 512);                                       \
  } while (0)

  f32x4 acc00 = {}, acc01 = {}, acc02 = {}, acc10 = {}, acc11 = {}, acc12 = {};
  const int xm = (l & 7) << 2;
  const int arow0 = l16 * 64, arow1 = (16 + l16) * 64;

  #define COMPUTE(bufi, B) do {                                                   \
    const int* Ab = Ash + (bufi) * 2048;                                          \
    _Pragma("unroll")                                                             \
    for (int s_ = 0; s_ < 2; ++s_) {                                              \
      const int ko = s_ * 32 + l4 * 8;                                            \
      i32x4 a0 = *(const i32x4*)&Ab[arow0 + ((ko + 0) ^ xm)];                     \
      i32x4 a1 = *(const i32x4*)&Ab[arow0 + ((ko + 4) ^ xm)];                     \
      i32x4 b0 = *(const i32x4*)&Ab[arow1 + ((ko + 0) ^ xm)];                     \
      i32x4 b1 = *(const i32x4*)&Ab[arow1 + ((ko + 4) ^ xm)];                     \
      bf16x8 af0 = __builtin_bit_cast(bf16x8, (i32x4){                            \
        (a0[0] | (a0[1] << 16)) * 0x3F80, (a0[2] | (a0[3] << 16)) * 0x3F80,       \
        (a1[0] | (a1[1] << 16)) * 0x3F80, (a1[2] | (a1[3] << 16)) * 0x3F80 });    \
      bf16x8 af1 = __builtin_bit_cast(bf16x8, (i32x4){                            \
        (b0[0] | (b0[1] << 16)) * 0x3F80, (b0[2] | (b0[3] << 16)) * 0x3F80,       \
        (b1[0] | (b1[1] << 16)) * 0x3F80, (b1[2] | (b1[3] << 16)) * 0x3F80 });    \
      acc00 = __builtin_amdgcn_mfma_f32_16x16x32_bf16(af0, B[0 + s_], acc00, 0, 0, 0); \
      acc01 = __builtin_amdgcn_mfma_f32_16x16x32_bf16(af0, B[2 + s_], acc01, 0, 0, 0); \
      acc02 = __builtin_amdgcn_mfma_f32_16x16x32_bf16(af0, B[4 + s_], acc02, 0, 0, 0); \
      acc10 = __builtin_amdgcn_mfma_f32_16x16x32_bf16(af1, B[0 + s_], acc10, 0, 0, 0); \
      acc11 = __builtin_amdgcn_mfma_f32_16x16x32_bf16(af1, B[2 + s_], acc11, 0, 0, 0); \
      acc12 = __builtin_amdgcn_mfma_f32_16x16x32_bf16(af1, B[4 + s_], acc12, 0, 0, 0); \
    }                                                                             \
  } while (0)

  bf16x8 B0[6], B1[6], B2[6];

  // prologue: chunks 0,1 in flight (16 loads/wave)
  STAGEA(0, 0); LOADB(B0, 0);
  STAGEA(1, 1); LOADB(B1, 1);

  #define ITER(kc, sbuf, cbuf, BL, BC) do {                                       \
    asm volatile("s_waitcnt vmcnt(8)" ::: "memory");                              \
    __builtin_amdgcn_s_barrier();                                                 \
    __builtin_amdgcn_sched_barrier(0);                                            \
    const int skc = ((kc) + 2 < KCH) ? (kc) + 2 : KCH - 1;                        \
    STAGEA(sbuf, skc); LOADB(BL, skc);                                            \
    COMPUTE(cbuf, BC);                                                            \
  } while (0)

  #pragma unroll 1
  for (int kc = 0; kc < KCH; kc += 3) {
    ITER(kc + 0, 2, 0, B2, B0);
    ITER(kc + 1, 0, 1, B0, B1);
    ITER(kc + 2, 1, 2, B1, B2);
  }

  // ---- partials to LDS; tile8 (V/deg) written by wave 0 only ----
  #pragma unroll
  for (int j = 0; j < 4; ++j) {
    red[(l4 * 4 + j) * 145 + (2 * wv + 0) * 16 + l16]      = acc00[j];
    red[(l4 * 4 + j) * 145 + (2 * wv + 1) * 16 + l16]      = acc01[j];
    red[(16 + l4 * 4 + j) * 145 + (2 * wv + 0) * 16 + l16] = acc10[j];
    red[(16 + l4 * 4 + j) * 145 + (2 * wv + 1) * 16 + l16] = acc11[j];
    if (wv == 0) {
      red[(l4 * 4 + j) * 145 + 128 + l16]      = acc02[j];
      red[(16 + l4 * 4 + j) * 145 + 128 + l16] = acc12[j];
    }
  }
  __syncthreads();

  if (t < 128) {
    int row = t >> 2, h = t & 3;
    float es = Es[((size_t)r * NNODE + ib + row) * NH + h];
    float V  = red[row * 145 + DOUT + h];
    float dg = red[row * 145 + DOUT + NH];
    coefL[t] = es / fmaf(es, V, (float)NNODE - dg) * (1.0f / NREL);
  }
  __syncthreads();

  #pragma unroll
  for (int idx = t; idx < 32 * DOUT; idx += 256) {
    int row = idx >> 7, c = idx & 127;
    atomicAdd(&out[(size_t)(ib + row) * DOUT + c],
              coefL[row * 4 + (c >> 5)] * red[row * 145 + c]);
  }
  #undef STAGEA
  #undef LOADB
  #undef COMPUTE
  #undef ITER
}

extern "C" void kernel_launch(void* const* d_in, const int* in_sizes, int n_in,
                              void* d_out, int out_size, void* d_ws, size_t ws_size,
                              hipStream_t stream) {
  const float* feat = (const float*)d_in[0];
  const int*   adj  = (const int*)d_in[1];
  const float* W    = (const float*)d_in[2];
  const float* av   = (const float*)d_in[3];
  const float* bias = (const float*)d_in[4];

  char* ws = (char*)d_ws;
  unsigned short* Mt = (unsigned short*)ws;                 // 3*48*9216*2  = 2,654,208 B
  float* Es = (float*)(ws + 2654208);                       // 3*3072*4*4   =   147,456 B
                                                            // total ws use: 2,801,664 B

  hipLaunchKernelGGL(k0_init, dim3(384), dim3(256), 0, stream, bias, (float*)d_out);
  hipLaunchKernelGGL(k1_prep, dim3(48, 3), dim3(256), 0, stream, feat, W, av, Mt, Es);
  hipLaunchKernelGGL(k2_agg,  dim3(96, 3), dim3(256), 0, stream, adj, Mt, Es, (float*)d_out);
}

// Round 5
// 64.865 us; speedup vs baseline: 1.0588x; 1.0588x over previous
//
#include <hip/hip_runtime.h>

typedef float  f32x4  __attribute__((ext_vector_type(4)));
typedef float  f32x2  __attribute__((ext_vector_type(2)));
typedef short  bf16x8 __attribute__((ext_vector_type(8)));
typedef int    i32x4  __attribute__((ext_vector_type(4)));

#define NNODE 3072
#define DIN   128
#define DOUT  128
#define NREL  3
#define NH    4
#define HD    32
#define KCH   48      // K chunks of 64
#define CHB   9216    // ushorts per B chunk (9 tiles * 2 steps * 64 lanes * 8)

static __device__ __forceinline__ unsigned short f2bf(float v) {
  unsigned u = __builtin_bit_cast(unsigned, v);
  u += 0x7FFFu + ((u >> 16) & 1u);          // round-to-nearest-even
  return (unsigned short)(u >> 16);
}

// ---------------- K0: init out = bias ----------------
__global__ __launch_bounds__(256, 1) void k0_init(
    const float* __restrict__ bias, float* __restrict__ out)
{
  const int tid = blockIdx.x * 256 + threadIdx.x;   // 3072*128/4 elems
  f32x4 b = *(const f32x4*)(bias + (tid & 31) * 4);
  *((f32x4*)out + tid) = b;
}

// ---------------- K1: t = F * W_r^T, attention scalars, build B in MFMA-fragment order ----
// grid (48, 3), block 256. Each block: one relation, 64 k-rows (= one 64-K chunk). (validated)
__global__ __launch_bounds__(256, 1) void k1_prep(
    const float* __restrict__ feat, const float* __restrict__ W,
    const float* __restrict__ av, unsigned short* __restrict__ Mt,
    float* __restrict__ Es)
{
  const int jt = blockIdx.x;     // 0..47  (= K chunk index)
  const int r  = blockIdx.y;     // 0..2
  const int t  = threadIdx.x;    // 0..255
  const int jb = jt * 64;

  __shared__ float Wl[128 * 130];
  __shared__ float Fl[64 * 129];
  __shared__ float Tl[64 * 129];
  __shared__ float El[64 * 5];

  const float* Wr = W + r * DOUT * DIN;
  for (int idx = t * 4; idx < DOUT * DIN; idx += 1024) {
    float4 v = *(const float4*)(Wr + idx);
    int o = idx >> 7, k = idx & 127;
    float* d = Wl + o * 130 + k;
    d[0] = v.x; d[1] = v.y; d[2] = v.z; d[3] = v.w;
  }
  for (int idx = t * 4; idx < 64 * DIN; idx += 1024) {
    float4 v = *(const float4*)(feat + (size_t)jb * DIN + idx);
    int n = idx >> 7, k = idx & 127;
    float* d = Fl + n * 129 + k;
    d[0] = v.x; d[1] = v.y; d[2] = v.z; d[3] = v.w;
  }
  __syncthreads();

  {
    const int ng = t & 15, og = t >> 4;
    float acc[4][8] = {};
    for (int k = 0; k < DIN; k += 4) {
      float wv[4][8];
      #pragma unroll
      for (int oo = 0; oo < 8; ++oo) {
        const float* wr2 = Wl + (og * 8 + oo) * 130 + k;
        f32x2 a01 = *(const f32x2*)wr2;
        f32x2 a23 = *(const f32x2*)(wr2 + 2);
        wv[0][oo] = a01[0]; wv[1][oo] = a01[1];
        wv[2][oo] = a23[0]; wv[3][oo] = a23[1];
      }
      #pragma unroll
      for (int nn = 0; nn < 4; ++nn) {
        const float* fr = Fl + (ng * 4 + nn) * 129 + k;
        float f0 = fr[0], f1 = fr[1], f2 = fr[2], f3 = fr[3];
        #pragma unroll
        for (int oo = 0; oo < 8; ++oo) {
          float s = acc[nn][oo];
          s = fmaf(f0, wv[0][oo], s);
          s = fmaf(f1, wv[1][oo], s);
          s = fmaf(f2, wv[2][oo], s);
          s = fmaf(f3, wv[3][oo], s);
          acc[nn][oo] = s;
        }
      }
    }
    #pragma unroll
    for (int nn = 0; nn < 4; ++nn)
      #pragma unroll
      for (int oo = 0; oo < 8; ++oo)
        Tl[(ng * 4 + nn) * 129 + og * 8 + oo] = acc[nn][oo];
  }
  __syncthreads();

  {
    const int n = t & 63, h = t >> 6;
    const float* tr = Tl + n * 129 + h * HD;
    const float* as = av + r * 2 * HD;
    float ss = 0.f, sd = 0.f;
    #pragma unroll
    for (int d = 0; d < HD; ++d) {
      float tvv = tr[d];
      ss = fmaf(tvv, as[d],      ss);
      sd = fmaf(tvv, as[HD + d], sd);
    }
    Es[((size_t)r * NNODE + jb + n) * NH + h] = expf(ss);
    El[n * 5 + h] = expf(sd);
  }
  __syncthreads();

  {
    // B fragment order: chunk = [tile nt][step s][lane = k8*16 + (c&15)][elem = j&7]
    const int n = t & 63, cb = t >> 6;   // j = jb + n
    unsigned short* base = Mt + ((size_t)r * KCH + jt) * CHB;
    const int s = n >> 5, k8 = (n >> 3) & 3, elem = n & 7;
    const int lanebase = k8 * 16;
    #pragma unroll
    for (int ci = 0; ci < 36; ++ci) {
      int c = cb * 36 + ci;
      float v;
      if (c < DOUT)            v = Tl[n * 129 + c] * El[n * 5 + (c >> 5)];
      else if (c < DOUT + NH)  v = El[n * 5 + (c - DOUT)];
      else if (c == DOUT + NH) v = 1.0f;
      else                     v = 0.0f;
      int nt = c >> 4;
      base[(nt * 2 + s) * 512 + (lanebase + (c & 15)) * 8 + elem] = f2bf(v);
    }
  }
}

// ---------------- K2: barrier-free wave-decoupled A@M, fused finalize ----------------
// grid (192, 3), block 256 = 4 waves. Block: 16 rows x 144 cols.
// Wave wv owns K chunks {wv, wv+4, ...} (12 chunks), all 9 col-tiles; A staged into
// WAVE-PRIVATE LDS dbuf via global_load_lds (vmcnt-ordered, no s_barrier in loop).
// Epilogue: cross-wave LDS reduce + coef + atomicAdd (validated pattern).
__global__ __launch_bounds__(256, 3) void k2_agg(
    const int* __restrict__ adj, const unsigned short* __restrict__ Mt,
    const float* __restrict__ Es, float* __restrict__ out)
{
  const int it = blockIdx.x;    // 0..191
  const int r  = blockIdx.y;    // 0..2
  const int t  = threadIdx.x;   // 0..255
  const int wv = t >> 6;        // 0..3
  const int l  = t & 63;
  const int l16 = l & 15, l4 = l >> 4;
  const int ib = it * 16;

  __shared__ __align__(16) int Ash[4][2][1024];  // [wave][buf][16 rows x 64 ints, swizzled]
  __shared__ float red[16 * 145];
  __shared__ float coefL[64];

  // A stage source pointers (4 instructions q: rows 4q..4q+3), chunk c0 = wv.
  // dest chunk (q*64+lane)/16 -> row 4q+(l>>4); src col-chunk = (l&15) ^ (row&7).
  const size_t adjBase = (size_t)r * NNODE * NNODE + (size_t)ib * NNODE;
  const int* asrc[4];
  #pragma unroll
  for (int q = 0; q < 4; ++q) {
    int row = q * 4 + l4;
    int chk = l16 ^ (row & 7);
    asrc[q] = adj + adjBase + (size_t)row * NNODE + wv * 64 + chk * 4;
  }
  const unsigned short* bp = Mt + (size_t)r * KCH * CHB + (size_t)wv * CHB + (size_t)l * 8;

  f32x4 acc[9] = {};
  bf16x8 B[9][2];
  int zero = 0;

  #define STAGE(bufi) do {                                                        \
    _Pragma("unroll")                                                             \
    for (int q = 0; q < 4; ++q)                                                   \
      __builtin_amdgcn_global_load_lds(                                           \
        (const __attribute__((address_space(1))) void*)asrc[q],                   \
        (__attribute__((address_space(3))) void*)&Ash[wv][bufi][q * 256], 16, 0, 0); \
  } while (0)

  STAGE(0);   // prologue: chunk wv into buf 0

  #pragma unroll 1
  for (int k = 0; k < 12; ++k) {
    // B for current chunk (18 x 1KB wave-contiguous loads)
    #pragma unroll
    for (int ti = 0; ti < 9; ++ti) {
      B[ti][0] = *(const bf16x8*)(bp + (ti * 2 + 0) * 512);
      B[ti][1] = *(const bf16x8*)(bp + (ti * 2 + 1) * 512);
    }
    bp += 4 * CHB;
    __builtin_amdgcn_sched_barrier(0);

    // stage next chunk (dummy re-stage on last iter to keep vmcnt count uniform)
    const int adv = (k < 11) ? 256 : 0;
    #pragma unroll
    for (int q = 0; q < 4; ++q) asrc[q] += adv;
    STAGE((k + 1) & 1);

    // wait: newest 4 outstanding = next-A stage; current A + all B complete.
    asm volatile("s_waitcnt vmcnt(4)" : "+v"(zero));
    __builtin_amdgcn_sched_barrier(0);

    const int* Ab = (const int*)((const char*)&Ash[wv][k & 1][0] + zero);
    #pragma unroll
    for (int s = 0; s < 2; ++s) {
      const int ko = s * 32 + l4 * 8;
      const int xm = (l & 7) << 2;
      i32x4 a0 = *(const i32x4*)&Ab[l16 * 64 + ((ko + 0) ^ xm)];
      i32x4 a1 = *(const i32x4*)&Ab[l16 * 64 + ((ko + 4) ^ xm)];
      bf16x8 af = __builtin_bit_cast(bf16x8, (i32x4){
        (a0[0] | (a0[1] << 16)) * 0x3F80, (a0[2] | (a0[3] << 16)) * 0x3F80,
        (a1[0] | (a1[1] << 16)) * 0x3F80, (a1[2] | (a1[3] << 16)) * 0x3F80 });
      #pragma unroll
      for (int ti = 0; ti < 9; ++ti)
        acc[ti] = __builtin_amdgcn_mfma_f32_16x16x32_bf16(af, B[ti][s], acc[ti], 0, 0, 0);
    }
  }

  // ---- cross-wave K reduction in LDS (sequential waves, syncthreads-ordered) ----
  if (wv == 0) {
    #pragma unroll
    for (int ti = 0; ti < 9; ++ti)
      #pragma unroll
      for (int rg = 0; rg < 4; ++rg)
        red[(l4 * 4 + rg) * 145 + ti * 16 + l16] = acc[ti][rg];
  }
  __syncthreads();
  #pragma unroll 1
  for (int w = 1; w < 4; ++w) {
    if (wv == w) {
      #pragma unroll
      for (int ti = 0; ti < 9; ++ti)
        #pragma unroll
        for (int rg = 0; rg < 4; ++rg)
          red[(l4 * 4 + rg) * 145 + ti * 16 + l16] += acc[ti][rg];
    }
    __syncthreads();
  }

  // ---- fused finalize: coef = e_src / (e_src*V + N - deg), folded 1/NREL ----
  if (t < 64) {
    int row = t >> 2, h = t & 3;
    float es = Es[((size_t)r * NNODE + ib + row) * NH + h];
    float V  = red[row * 145 + DOUT + h];
    float dg = red[row * 145 + DOUT + NH];
    coefL[t] = es / fmaf(es, V, (float)NNODE - dg) * (1.0f / NREL);
  }
  __syncthreads();

  #pragma unroll
  for (int idx = t; idx < 16 * DOUT; idx += 256) {
    int row = idx >> 7, c = idx & 127;
    atomicAdd(&out[(size_t)(ib + row) * DOUT + c],
              coefL[row * 4 + (c >> 5)] * red[row * 145 + c]);
  }
  #undef STAGE
}

extern "C" void kernel_launch(void* const* d_in, const int* in_sizes, int n_in,
                              void* d_out, int out_size, void* d_ws, size_t ws_size,
                              hipStream_t stream) {
  const float* feat = (const float*)d_in[0];
  const int*   adj  = (const int*)d_in[1];
  const float* W    = (const float*)d_in[2];
  const float* av   = (const float*)d_in[3];
  const float* bias = (const float*)d_in[4];

  char* ws = (char*)d_ws;
  unsigned short* Mt = (unsigned short*)ws;                 // 3*48*9216*2  = 2,654,208 B
  float* Es = (float*)(ws + 2654208);                       // 3*3072*4*4   =   147,456 B
                                                            // total ws use: 2,801,664 B

  hipLaunchKernelGGL(k0_init, dim3(384), dim3(256), 0, stream, bias, (float*)d_out);
  hipLaunchKernelGGL(k1_prep, dim3(48, 3), dim3(256), 0, stream, feat, W, av, Mt, Es);
  hipLaunchKernelGGL(k2_agg,  dim3(192, 3), dim3(256), 0, stream, adj, Mt, Es, (float*)d_out);
}